// Round 7
// baseline (266.828 us; speedup 1.0000x reference)
//
#include <hip/hip_runtime.h>
#include <hip/hip_bf16.h>

#define MDIM 16384
#define NDIM 1024
#define KDIM 512
#define BM 128
#define BN 128
#define BK 64
#define KT (KDIM / BK)   // 8

typedef __attribute__((ext_vector_type(8))) short bf16x8;
typedef __attribute__((ext_vector_type(4))) short bf16x4;
typedef __attribute__((ext_vector_type(4))) float f32x4;

__device__ __forceinline__ short f2bf(float f) {
    union { float f; unsigned u; } v; v.f = f;
    unsigned r = v.u + 0x7fff + ((v.u >> 16) & 1);   // RNE truncate to bf16
    return (short)(r >> 16);
}

// ---------- fully fused kernel: convert + sumsq + GEMM + epilogue ----------
// One kernel, no workspace. Each block reg-stages its fp32 A/B tiles,
// converts to bf16 LDS (symmetric XOR swizzle, write+read both in-kernel),
// and accumulates exact fp32 sum-of-squares during staging (each element
// passes through registers exactly once across the 8 K-tiles). Per-row
// sums finish with a 16-lane shfl_xor reduce into small LDS arrays.
// T14 ordering per tile: issue loads(t+1) -> compute(t) -> cvt+write(t+1)
// -> one barrier. Double-buffered; writes always target the dead buffer.
__global__ __launch_bounds__(256, 2) void dist_fused(
        const float* __restrict__ X, const float* __restrict__ P,
        float* __restrict__ out) {
    __shared__ short As[2][BM * BK];   // 2 x 16 KB
    __shared__ short Bs[2][BN * BK];   // 2 x 16 KB  (64 KB -> 2 blocks/CU)
    __shared__ float xs_l[BM];
    __shared__ float ps_l[BN];

    int tid = threadIdx.x;
    int bid = blockIdx.x;
    // bijective XCD swizzle: nwg = 1024, chunks of 128; consecutive swz share
    // bm -> 8 N-blocks of one A-panel co-resident per XCD (L2/L3 reuse of the
    // fp32 A re-reads).
    int swz = (bid & 7) * 128 + (bid >> 3);
    int bn = swz & 7, bm = swz >> 3;
    int row0 = bm * BM, col0 = bn * BN;

    int lane = tid & 63, wid = tid >> 6;
    int wm = (wid >> 1) * 64, wn = (wid & 1) * 64;   // 2x2 waves, 64x64 each

    f32x4 acc[4][4] = {};
    float ssqA[8] = {}, ssqB[8] = {};
    float4 ra[8], rb[8];                 // in-flight fp32 staging (64 VGPR)

    const float* Abase = X + (size_t)row0 * KDIM;
    const float* Bbase = P + (size_t)col0 * KDIM;

    // staging geometry: chunk c = i*256+tid (16B fp32); row = 16i + (tid>>4),
    // col4 = tid&15  (each row's 64 floats = 16 chunks; lanes 0-15 contiguous)
    int g = tid >> 4, c4 = tid & 15;

    auto loadT = [&](int kt) {
        #pragma unroll
        for (int i = 0; i < 8; ++i) {
            int row = 16 * i + g;
            ra[i] = *(const float4*)(Abase + (size_t)row * KDIM + kt * BK + c4 * 4);
            rb[i] = *(const float4*)(Bbase + (size_t)row * KDIM + kt * BK + c4 * 4);
        }
    };
    // cvt + swizzled LDS write + exact fp32 ssq accumulation
    auto commitT = [&](int sel) {
        #pragma unroll
        for (int i = 0; i < 8; ++i) {
            int row = 16 * i + g;
            int off = (row * (BK * 2) + c4 * 8) ^ ((row & 7) << 4);
            float4 a = ra[i], b = rb[i];
            ssqA[i] += a.x * a.x + a.y * a.y + a.z * a.z + a.w * a.w;
            ssqB[i] += b.x * b.x + b.y * b.y + b.z * b.z + b.w * b.w;
            bf16x4 av, bv;
            av[0] = f2bf(a.x); av[1] = f2bf(a.y); av[2] = f2bf(a.z); av[3] = f2bf(a.w);
            bv[0] = f2bf(b.x); bv[1] = f2bf(b.y); bv[2] = f2bf(b.z); bv[3] = f2bf(b.w);
            *(bf16x4*)((char*)&As[sel][0] + off) = av;
            *(bf16x4*)((char*)&Bs[sel][0] + off) = bv;
        }
    };

    auto lds_off = [&](int row, int kb) {
        return (row * (BK * 2) + kb) ^ ((row & 7) << 4);
    };
    auto compute = [&](int sel) {
        const char* aB = (const char*)&As[sel][0];
        const char* bB = (const char*)&Bs[sel][0];
        #pragma unroll
        for (int ks = 0; ks < 2; ++ks) {
            int kb = ks * 64 + ((lane >> 4) * 16);
            bf16x8 af[4], bfr[4];
            #pragma unroll
            for (int m = 0; m < 4; ++m)
                af[m] = *(const bf16x8*)(aB + lds_off(wm + m * 16 + (lane & 15), kb));
            #pragma unroll
            for (int n = 0; n < 4; ++n)
                bfr[n] = *(const bf16x8*)(bB + lds_off(wn + n * 16 + (lane & 15), kb));
            #pragma unroll
            for (int m = 0; m < 4; ++m)
                #pragma unroll
                for (int n = 0; n < 4; ++n)
                    acc[m][n] = __builtin_amdgcn_mfma_f32_16x16x32_bf16(
                        af[m], bfr[n], acc[m][n], 0, 0, 0);
        }
    };

    // prologue: tile 0 -> buf 0
    loadT(0);
    commitT(0);
    __syncthreads();
    int cur = 0;
    #pragma unroll
    for (int t = 0; t < KT - 1; ++t) {
        loadT(t + 1);        // issue early: HBM latency hides under compute (T14)
        compute(cur);        // MFMA on resident tile
        commitT(cur ^ 1);    // vmcnt wait via data dep; writes dead buffer
        __syncthreads();     // writes visible; buf roles flip
        cur ^= 1;
    }
    compute(cur);            // last tile

    // finish sum-of-squares: rows 16i+g owned by the 16 threads sharing g
    #pragma unroll
    for (int i = 0; i < 8; ++i) {
        float sa = ssqA[i], sb = ssqB[i];
        #pragma unroll
        for (int m = 1; m < 16; m <<= 1) {
            sa += __shfl_xor(sa, m, 64);
            sb += __shfl_xor(sb, m, 64);
        }
        if (c4 == 0) {
            xs_l[16 * i + g] = sa;
            ps_l[16 * i + g] = sb;
        }
    }
    __syncthreads();

    // epilogue: C/D layout col = lane&15, row = (lane>>4)*4 + reg  [m89]
    int cr = (lane >> 4) * 4;
    int cc = lane & 15;
    float ps[4];
    #pragma unroll
    for (int n = 0; n < 4; ++n) ps[n] = ps_l[wn + n * 16 + cc];
    #pragma unroll
    for (int m = 0; m < 4; ++m) {
        int lr = wm + m * 16 + cr;
        #pragma unroll
        for (int r = 0; r < 4; ++r) {
            float xv = xs_l[lr + r];
            size_t ob = (size_t)(row0 + lr + r) * NDIM + col0;
            #pragma unroll
            for (int n = 0; n < 4; ++n) {
                int lc = wn + n * 16 + cc;
                out[ob + lc] = 2.0f * acc[m][n][r] - xv - ps[n];
            }
        }
    }
}

extern "C" void kernel_launch(void* const* d_in, const int* in_sizes, int n_in,
                              void* d_out, int out_size, void* d_ws, size_t ws_size,
                              hipStream_t stream) {
    const float* X = (const float*)d_in[0];
    const float* P = (const float*)d_in[1];
    float* out = (float*)d_out;
    dist_fused<<<(MDIM / BM) * (NDIM / BN), 256, 0, stream>>>(X, P, out);
}

// Round 8
// 51.515 us; speedup vs baseline: 5.1796x; 5.1796x over previous
//
#include <hip/hip_runtime.h>
#include <hip/hip_bf16.h>

#define MDIM 16384
#define NDIM 1024
#define KDIM 512
#define ROWS 64            // rows owned per block (persistent)
#define BN 256             // column tile per bn-iteration
#define BK 64
#define NBN (NDIM / BN)    // 4
#define KT (KDIM / BK)     // 8

typedef __attribute__((ext_vector_type(8))) short bf16x8;
typedef __attribute__((ext_vector_type(4))) short bf16x4;
typedef __attribute__((ext_vector_type(4))) float f32x4;

__device__ __forceinline__ short f2bf(float f) {
    union { float f; unsigned u; } v; v.f = f;
    unsigned r = v.u + 0x7fff + ((v.u >> 16) & 1);   // RNE truncate to bf16
    return (short)(r >> 16);
}

__device__ __forceinline__ void gload_lds16(const void* g, void* l) {
    __builtin_amdgcn_global_load_lds(
        (const __attribute__((address_space(1))) void*)g,
        (__attribute__((address_space(3))) void*)l, 16, 0, 0);
}

// ---------- tiny pre-kernel: P fp32 -> bf16 + exact psq (one wave/row) ----------
__global__ __launch_bounds__(256) void convert_p(
        const float* __restrict__ P, short* __restrict__ Pbf,
        float* __restrict__ psq) {
    int wave = (blockIdx.x * blockDim.x + threadIdx.x) >> 6;   // 0..1023
    int lane = threadIdx.x & 63;
    const float4* r4 = (const float4*)(P + (size_t)wave * KDIM) + lane * 2;
    float4 a = r4[0], b = r4[1];
    bf16x8 o;
    o[0] = f2bf(a.x); o[1] = f2bf(a.y); o[2] = f2bf(a.z); o[3] = f2bf(a.w);
    o[4] = f2bf(b.x); o[5] = f2bf(b.y); o[6] = f2bf(b.z); o[7] = f2bf(b.w);
    *(bf16x8*)(Pbf + (size_t)wave * KDIM + lane * 8) = o;
    float s = a.x*a.x + a.y*a.y + a.z*a.z + a.w*a.w
            + b.x*b.x + b.y*b.y + b.z*b.z + b.w*b.w;
    #pragma unroll
    for (int off = 32; off; off >>= 1) s += __shfl_down(s, off, 64);
    if (lane == 0) psq[wave] = s;
}

// ---------- persistent row-panel kernel ----------
// Block owns 64 rows x all 1024 cols. A-panel converted ONCE into K-complete
// LDS (64KB, symmetric XOR swizzle, exact fp32 xsq on the fly, nothing held
// across compute). Then 4 bn-iterations: B tiles staged via gload_lds w16
// (linear dest + pre-XOR source, rule #21), double-buffered 2-phase, 64KB
// store burst per bn interleaved with the next bn's K-loop.
__global__ __launch_bounds__(256, 1) void dist_persist(
        const float* __restrict__ X, const short* __restrict__ Pbf,
        const float* __restrict__ psq, float* __restrict__ out) {
    __shared__ short Al[ROWS * KDIM];     // 64 KB, K-complete A panel
    __shared__ short Bsl[2][BN * BK];     // 2 x 32 KB
    __shared__ float xs_l[ROWS];

    int tid = threadIdx.x;
    int bid = blockIdx.x;                 // 256 blocks, disjoint row panels
    int row0 = bid * ROWS;

    int lane = tid & 63, wid = tid >> 6;
    int wc = wid;                         // 4 waves, 1M x 4N; wave = 64x64

    // stage B tile (bnb, kt) into buffer sel: 8 gload16/thread (32 KB)
    auto stageB = [&](int sel, int bnb, int kt) {
        #pragma unroll
        for (int s = 0; s < 8; ++s) {
            int c = s * 256 + tid;               // chunk 0..2047
            int row = c >> 3;                    // 0..255
            int g16 = (c & 7) ^ (row & 7);       // pre-swizzled source slot
            const char* gb = (const char*)(Pbf + (size_t)(bnb * BN + row) * KDIM)
                             + kt * (BK * 2) + g16 * 16;
            gload_lds16(gb, (char*)&Bsl[sel][0] + s * 4096 + wid * 1024);
        }
    };

    // prologue: first B tile in flight while we convert A
    stageB(0, 0, 0);

    // A-phase: 4 threads per row, 128 fp32 each; cvt+swizzled ds_write + ssq
    {
        int arow = tid >> 2, q = tid & 3;
        const float4* rp = (const float4*)(X + (size_t)(row0 + arow) * KDIM);
        float ssq = 0.f;
        #pragma unroll
        for (int i = 0; i < 32; ++i) {
            int col4 = i * 4 + q;                // lanes q=0..3 -> 64B coalesced
            float4 a = rp[col4];
            ssq += a.x * a.x + a.y * a.y + a.z * a.z + a.w * a.w;
            bf16x4 av;
            av[0] = f2bf(a.x); av[1] = f2bf(a.y); av[2] = f2bf(a.z); av[3] = f2bf(a.w);
            int off = (arow * (KDIM * 2) + col4 * 8) ^ ((arow & 7) << 4);
            *(bf16x4*)((char*)Al + off) = av;
        }
        ssq += __shfl_xor(ssq, 1, 64);
        ssq += __shfl_xor(ssq, 2, 64);
        if (q == 0) xs_l[arow] = ssq;
    }
    __syncthreads();   // A panel + xsq + B(0,0) all resident

    int cr = (lane >> 4) * 4;
    int cc = lane & 15;

    #pragma unroll 1
    for (int bn = 0; bn < NBN; ++bn) {
        f32x4 acc[4][4] = {};
        #pragma unroll
        for (int kt = 0; kt < KT; ++kt) {
            int buf = kt & 1;
            // issue next tile's B loads first (in flight across this compute)
            if (kt < KT - 1)            stageB(buf ^ 1, bn, kt + 1);
            else if (bn < NBN - 1)      stageB(buf ^ 1, bn + 1, 0);
            // compute: A(kt) x B[buf]
            const char* aB = (const char*)Al;
            const char* bB = (const char*)&Bsl[buf][0];
            #pragma unroll
            for (int ks = 0; ks < 2; ++ks) {
                int kbB = ks * 64 + ((lane >> 4) * 16);
                int kbA = kt * 128 + kbB;
                bf16x8 af[4], bfr[4];
                #pragma unroll
                for (int m = 0; m < 4; ++m) {
                    int row = m * 16 + (lane & 15);
                    af[m] = *(const bf16x8*)(aB +
                        ((row * (KDIM * 2) + kbA) ^ ((row & 7) << 4)));
                }
                #pragma unroll
                for (int n = 0; n < 4; ++n) {
                    int row = wc * 64 + n * 16 + (lane & 15);
                    bfr[n] = *(const bf16x8*)(bB +
                        ((row * (BK * 2) + kbB) ^ ((row & 7) << 4)));
                }
                #pragma unroll
                for (int m = 0; m < 4; ++m)
                    #pragma unroll
                    for (int n = 0; n < 4; ++n)
                        acc[m][n] = __builtin_amdgcn_mfma_f32_16x16x32_bf16(
                            af[m], bfr[n], acc[m][n], 0, 0, 0);
            }
            if (kt == KT - 1) {
                // epilogue for this bn: fire stores, then barrier gates next bn
                float ps[4];
                #pragma unroll
                for (int n = 0; n < 4; ++n)
                    ps[n] = psq[bn * BN + wc * 64 + n * 16 + cc];
                #pragma unroll
                for (int m = 0; m < 4; ++m) {
                    #pragma unroll
                    for (int r = 0; r < 4; ++r) {
                        int lr = m * 16 + cr + r;
                        float xv = xs_l[lr];
                        size_t ob = (size_t)(row0 + lr) * NDIM + bn * BN;
                        #pragma unroll
                        for (int n = 0; n < 4; ++n)
                            out[ob + wc * 64 + n * 16 + cc] =
                                2.0f * acc[m][n][r] - xv - ps[n];
                    }
                }
            }
            if (!(bn == NBN - 1 && kt == KT - 1))
                __syncthreads();   // stage loads resident; buffer roles flip
        }
    }
}

// ---------- fallback path (R1-verified fp32 kernels, used if ws too small) ----------
__global__ __launch_bounds__(256) void sumsq_kernel(
        const float* __restrict__ X, const float* __restrict__ P,
        float* __restrict__ xsq, float* __restrict__ psq) {
    int wave = (blockIdx.x * blockDim.x + threadIdx.x) >> 6;
    int lane = threadIdx.x & 63;
    const float* src; float* dst; int row;
    if (wave < MDIM) { src = X; dst = xsq; row = wave; }
    else             { src = P; dst = psq; row = wave - MDIM; }
    const float4* r4 = (const float4*)(src + (size_t)row * KDIM) + lane * 2;
    float4 a = r4[0], b = r4[1];
    float s = a.x*a.x + a.y*a.y + a.z*a.z + a.w*a.w
            + b.x*b.x + b.y*b.y + b.z*b.z + b.w*b.w;
    #pragma unroll
    for (int off = 32; off; off >>= 1) s += __shfl_down(s, off, 64);
    if (lane == 0) dst[row] = s;
}

__device__ __forceinline__ bf16x8 cvt8(float4 a, float4 b) {
    bf16x8 o;
    o[0] = f2bf(a.x); o[1] = f2bf(a.y); o[2] = f2bf(a.z); o[3] = f2bf(a.w);
    o[4] = f2bf(b.x); o[5] = f2bf(b.y); o[6] = f2bf(b.z); o[7] = f2bf(b.w);
    return o;
}

__global__ __launch_bounds__(256) void dist_gemm(
        const float* __restrict__ X, const float* __restrict__ P,
        const float* __restrict__ xsq, const float* __restrict__ psq,
        float* __restrict__ out) {
    __shared__ short As[128 * BK];
    __shared__ short Bs[128 * BK];
    int tid = threadIdx.x;
    int bid = blockIdx.x;
    int swz = (bid & 7) * 128 + (bid >> 3);
    int bn = swz & 7, bm = swz >> 3;
    int row0 = bm * 128, col0 = bn * 128;
    int lane = tid & 63, wid = tid >> 6;
    int wm = (wid >> 1) * 64, wn = (wid & 1) * 64;
    f32x4 acc[4][4] = {};
    int rbase = tid >> 3;
    int kg = tid & 7;
    const float* Abase = X + (size_t)row0 * KDIM;
    const float* Bbase = P + (size_t)col0 * KDIM;
    for (int kt = 0; kt < KDIM / BK; ++kt) {
        int kofs = kt * BK + kg * 8;
        __syncthreads();
        #pragma unroll
        for (int i = 0; i < 4; ++i) {
            int row = rbase + 32 * i;
            const float4* ga = (const float4*)(Abase + (size_t)row * KDIM + kofs);
            float4 a0 = ga[0], a1 = ga[1];
            const float4* gb = (const float4*)(Bbase + (size_t)row * KDIM + kofs);
            float4 b0 = gb[0], b1 = gb[1];
            int off = (row * (BK * 2) + kg * 16) ^ ((row & 7) << 4);
            *(bf16x8*)((char*)As + off) = cvt8(a0, a1);
            *(bf16x8*)((char*)Bs + off) = cvt8(b0, b1);
        }
        __syncthreads();
        #pragma unroll
        for (int ks = 0; ks < 2; ++ks) {
            bf16x8 af[4], bfr[4];
            int kb = ks * 64 + ((lane >> 4) * 16);
            #pragma unroll
            for (int m = 0; m < 4; ++m) {
                int row = wm + m * 16 + (lane & 15);
                int off = (row * (BK * 2) + kb) ^ ((row & 7) << 4);
                af[m] = *(const bf16x8*)((const char*)As + off);
            }
            #pragma unroll
            for (int n = 0; n < 4; ++n) {
                int row = wn + n * 16 + (lane & 15);
                int off = (row * (BK * 2) + kb) ^ ((row & 7) << 4);
                bfr[n] = *(const bf16x8*)((const char*)Bs + off);
            }
            #pragma unroll
            for (int m = 0; m < 4; ++m)
                #pragma unroll
                for (int n = 0; n < 4; ++n)
                    acc[m][n] = __builtin_amdgcn_mfma_f32_16x16x32_bf16(
                        af[m], bfr[n], acc[m][n], 0, 0, 0);
        }
    }
    int cr = (lane >> 4) * 4;
    int cc = lane & 15;
    #pragma unroll
    for (int n = 0; n < 4; ++n) {
        int gc = col0 + wn + n * 16 + cc;
        float ps = psq[gc];
        #pragma unroll
        for (int m = 0; m < 4; ++m) {
            int grb = row0 + wm + m * 16 + cr;
            #pragma unroll
            for (int r = 0; r < 4; ++r) {
                float v = 2.0f * acc[m][n][r] - xsq[grb + r] - ps;
                out[(size_t)(grb + r) * NDIM + gc] = v;
            }
        }
    }
}

extern "C" void kernel_launch(void* const* d_in, const int* in_sizes, int n_in,
                              void* d_out, int out_size, void* d_ws, size_t ws_size,
                              hipStream_t stream) {
    const float* X = (const float*)d_in[0];
    const float* P = (const float*)d_in[1];
    float* out = (float*)d_out;

    const size_t need = (size_t)NDIM * KDIM * 2 + (size_t)NDIM * 4;  // Pbf + psq

    if (ws_size >= need) {
        short* Pbf = (short*)d_ws;                       // 1 MB
        float* psq = (float*)(Pbf + (size_t)NDIM * KDIM); // 4 KB
        convert_p<<<NDIM / 4, 256, 0, stream>>>(P, Pbf, psq);
        dist_persist<<<MDIM / ROWS, 256, 0, stream>>>(X, Pbf, psq, out);
    } else {
        float* xsq = (float*)d_ws;
        float* psq = xsq + MDIM;
        sumsq_kernel<<<(MDIM + NDIM) / 4, 256, 0, stream>>>(X, P, xsq, psq);
        dist_gemm<<<(MDIM / 128) * (NDIM / 128), 256, 0, stream>>>(X, P, xsq, psq, out);
    }
}

// Round 9
// 48.428 us; speedup vs baseline: 5.5098x; 1.0637x over previous
//
#include <hip/hip_runtime.h>
#include <hip/hip_bf16.h>

#define MDIM 16384
#define NDIM 1024
#define KDIM 512
#define ROWS 64            // rows owned per block (persistent)
#define BN 256             // column tile per bn-iteration
#define BK 64
#define NBN (NDIM / BN)    // 4
#define KT (KDIM / BK)     // 8

typedef __attribute__((ext_vector_type(8))) short bf16x8;
typedef __attribute__((ext_vector_type(4))) short bf16x4;
typedef __attribute__((ext_vector_type(4))) float f32x4;

__device__ __forceinline__ short f2bf(float f) {
    union { float f; unsigned u; } v; v.f = f;
    unsigned r = v.u + 0x7fff + ((v.u >> 16) & 1);   // RNE truncate to bf16
    return (short)(r >> 16);
}

__device__ __forceinline__ void gload_lds16(const void* g, void* l) {
    __builtin_amdgcn_global_load_lds(
        (const __attribute__((address_space(1))) void*)g,
        (__attribute__((address_space(3))) void*)l, 16, 0, 0);
}

// ---------- tiny pre-kernel: P fp32 -> bf16 + exact psq (one wave/row) ----------
__global__ __launch_bounds__(256) void convert_p(
        const float* __restrict__ P, short* __restrict__ Pbf,
        float* __restrict__ psq) {
    int wave = (blockIdx.x * blockDim.x + threadIdx.x) >> 6;   // 0..1023
    int lane = threadIdx.x & 63;
    const float4* r4 = (const float4*)(P + (size_t)wave * KDIM) + lane * 2;
    float4 a = r4[0], b = r4[1];
    bf16x8 o;
    o[0] = f2bf(a.x); o[1] = f2bf(a.y); o[2] = f2bf(a.z); o[3] = f2bf(a.w);
    o[4] = f2bf(b.x); o[5] = f2bf(b.y); o[6] = f2bf(b.z); o[7] = f2bf(b.w);
    *(bf16x8*)(Pbf + (size_t)wave * KDIM + lane * 8) = o;
    float s = a.x*a.x + a.y*a.y + a.z*a.z + a.w*a.w
            + b.x*b.x + b.y*b.y + b.z*b.z + b.w*b.w;
    #pragma unroll
    for (int off = 32; off; off >>= 1) s += __shfl_down(s, off, 64);
    if (lane == 0) psq[wave] = s;
}

// ---------- persistent row-panel kernel, 512 threads / 8 waves ----------
// Block owns 64 rows x all 1024 cols. A-panel converted ONCE into K-complete
// LDS (64KB, symmetric XOR swizzle, exact fp32 xsq on the fly). 4 bn-iters:
// B tiles staged via gload_lds w16 (linear dest + pre-XOR source, rule #21),
// double-buffered, per-bn 64KB store burst interleaved with next bn's K-loop.
// R8 post-mortem: identical structure at 256 thr was latency-bound at 1
// wave/SIMD (Occ 8.7%); 512 thr puts 2 waves/SIMD = the measured knee.
__global__ __launch_bounds__(512, 2) void dist_persist(
        const float* __restrict__ X, const short* __restrict__ Pbf,
        const float* __restrict__ psq, float* __restrict__ out) {
    __shared__ short Al[ROWS * KDIM];     // 64 KB, K-complete A panel
    __shared__ short Bsl[2][BN * BK];     // 2 x 32 KB
    __shared__ float xs_l[ROWS];

    int tid = threadIdx.x;
    int bid = blockIdx.x;                 // 256 blocks, disjoint row panels
    int row0 = bid * ROWS;

    int lane = tid & 63, wid = tid >> 6;
    int wr = wid >> 2, wc = wid & 3;      // 2(M) x 4(N); wave = 32 rows x 64 cols

    // stage B tile (bnb, kt) into buffer sel: 4 gload16/thread (32 KB)
    auto stageB = [&](int sel, int bnb, int kt) {
        #pragma unroll
        for (int s = 0; s < 4; ++s) {
            int c = s * 512 + tid;               // chunk 0..2047
            int row = c >> 3;                    // 0..255
            int g16 = (c & 7) ^ (row & 7);       // pre-swizzled source slot
            const char* gb = (const char*)(Pbf + (size_t)(bnb * BN + row) * KDIM)
                             + kt * (BK * 2) + g16 * 16;
            gload_lds16(gb, (char*)&Bsl[sel][0] + s * 8192 + wid * 1024);
        }
    };

    // prologue: first B tile in flight while we convert A
    stageB(0, 0, 0);

    // A-phase: 8 threads per row, 64 fp32 each; cvt + swizzled ds_write + ssq
    {
        int arow = tid >> 3, q = tid & 7;
        const float4* rp = (const float4*)(X + (size_t)(row0 + arow) * KDIM);
        float ssq = 0.f;
        #pragma unroll
        for (int i = 0; i < 16; ++i) {
            int col4 = i * 8 + q;                // lanes q=0..7 -> 128B coalesced
            float4 a = rp[col4];
            ssq += a.x * a.x + a.y * a.y + a.z * a.z + a.w * a.w;
            bf16x4 av;
            av[0] = f2bf(a.x); av[1] = f2bf(a.y); av[2] = f2bf(a.z); av[3] = f2bf(a.w);
            int off = (arow * (KDIM * 2) + col4 * 8) ^ ((arow & 7) << 4);
            *(bf16x4*)((char*)Al + off) = av;
        }
        ssq += __shfl_xor(ssq, 1, 64);
        ssq += __shfl_xor(ssq, 2, 64);
        ssq += __shfl_xor(ssq, 4, 64);
        if (q == 0) xs_l[arow] = ssq;
    }
    __syncthreads();   // A panel + xsq + B(0,0) all resident

    int cr = (lane >> 4) * 4;
    int cc = lane & 15;

    #pragma unroll 1
    for (int bn = 0; bn < NBN; ++bn) {
        f32x4 acc[2][4] = {};
        #pragma unroll
        for (int kt = 0; kt < KT; ++kt) {
            int buf = kt & 1;
            // issue next tile's B loads first (in flight across this compute)
            if (kt < KT - 1)            stageB(buf ^ 1, bn, kt + 1);
            else if (bn < NBN - 1)      stageB(buf ^ 1, bn + 1, 0);
            // compute: A(kt) x B[buf]
            const char* aB = (const char*)Al;
            const char* bB = (const char*)&Bsl[buf][0];
            #pragma unroll
            for (int ks = 0; ks < 2; ++ks) {
                int kbB = ks * 64 + ((lane >> 4) * 16);
                int kbA = kt * 128 + kbB;
                bf16x8 af[2], bfr[4];
                #pragma unroll
                for (int m = 0; m < 2; ++m) {
                    int row = wr * 32 + m * 16 + (lane & 15);
                    af[m] = *(const bf16x8*)(aB +
                        ((row * (KDIM * 2) + kbA) ^ ((row & 7) << 4)));
                }
                #pragma unroll
                for (int n = 0; n < 4; ++n) {
                    int row = wc * 64 + n * 16 + (lane & 15);
                    bfr[n] = *(const bf16x8*)(bB +
                        ((row * (BK * 2) + kbB) ^ ((row & 7) << 4)));
                }
                #pragma unroll
                for (int m = 0; m < 2; ++m)
                    #pragma unroll
                    for (int n = 0; n < 4; ++n)
                        acc[m][n] = __builtin_amdgcn_mfma_f32_16x16x32_bf16(
                            af[m], bfr[n], acc[m][n], 0, 0, 0);
            }
            if (kt == KT - 1) {
                // epilogue for this bn: fire stores, then barrier gates next bn
                float ps[4];
                #pragma unroll
                for (int n = 0; n < 4; ++n)
                    ps[n] = psq[bn * BN + wc * 64 + n * 16 + cc];
                #pragma unroll
                for (int m = 0; m < 2; ++m) {
                    #pragma unroll
                    for (int r = 0; r < 4; ++r) {
                        int lr = wr * 32 + m * 16 + cr + r;
                        float xv = xs_l[lr];
                        size_t ob = (size_t)(row0 + lr) * NDIM + bn * BN;
                        #pragma unroll
                        for (int n = 0; n < 4; ++n)
                            out[ob + wc * 64 + n * 16 + cc] =
                                2.0f * acc[m][n][r] - xv - ps[n];
                    }
                }
            }
            if (!(bn == NBN - 1 && kt == KT - 1))
                __syncthreads();   // stage loads resident; buffer roles flip
        }
    }
}

// ---------- fallback path (R1-verified fp32 kernels, used if ws too small) ----------
__global__ __launch_bounds__(256) void sumsq_kernel(
        const float* __restrict__ X, const float* __restrict__ P,
        float* __restrict__ xsq, float* __restrict__ psq) {
    int wave = (blockIdx.x * blockDim.x + threadIdx.x) >> 6;
    int lane = threadIdx.x & 63;
    const float* src; float* dst; int row;
    if (wave < MDIM) { src = X; dst = xsq; row = wave; }
    else             { src = P; dst = psq; row = wave - MDIM; }
    const float4* r4 = (const float4*)(src + (size_t)row * KDIM) + lane * 2;
    float4 a = r4[0], b = r4[1];
    float s = a.x*a.x + a.y*a.y + a.z*a.z + a.w*a.w
            + b.x*b.x + b.y*b.y + b.z*b.z + b.w*b.w;
    #pragma unroll
    for (int off = 32; off; off >>= 1) s += __shfl_down(s, off, 64);
    if (lane == 0) dst[row] = s;
}

__device__ __forceinline__ bf16x8 cvt8(float4 a, float4 b) {
    bf16x8 o;
    o[0] = f2bf(a.x); o[1] = f2bf(a.y); o[2] = f2bf(a.z); o[3] = f2bf(a.w);
    o[4] = f2bf(b.x); o[5] = f2bf(b.y); o[6] = f2bf(b.z); o[7] = f2bf(b.w);
    return o;
}

__global__ __launch_bounds__(256) void dist_gemm(
        const float* __restrict__ X, const float* __restrict__ P,
        const float* __restrict__ xsq, const float* __restrict__ psq,
        float* __restrict__ out) {
    __shared__ short As[128 * BK];
    __shared__ short Bs[128 * BK];
    int tid = threadIdx.x;
    int bid = blockIdx.x;
    int swz = (bid & 7) * 128 + (bid >> 3);
    int bn = swz & 7, bm = swz >> 3;
    int row0 = bm * 128, col0 = bn * 128;
    int lane = tid & 63, wid = tid >> 6;
    int wm = (wid >> 1) * 64, wn = (wid & 1) * 64;
    f32x4 acc[4][4] = {};
    int rbase = tid >> 3;
    int kg = tid & 7;
    const float* Abase = X + (size_t)row0 * KDIM;
    const float* Bbase = P + (size_t)col0 * KDIM;
    for (int kt = 0; kt < KDIM / BK; ++kt) {
        int kofs = kt * BK + kg * 8;
        __syncthreads();
        #pragma unroll
        for (int i = 0; i < 4; ++i) {
            int row = rbase + 32 * i;
            const float4* ga = (const float4*)(Abase + (size_t)row * KDIM + kofs);
            float4 a0 = ga[0], a1 = ga[1];
            const float4* gb = (const float4*)(Bbase + (size_t)row * KDIM + kofs);
            float4 b0 = gb[0], b1 = gb[1];
            int off = (row * (BK * 2) + kg * 16) ^ ((row & 7) << 4);
            *(bf16x8*)((char*)As + off) = cvt8(a0, a1);
            *(bf16x8*)((char*)Bs + off) = cvt8(b0, b1);
        }
        __syncthreads();
        #pragma unroll
        for (int ks = 0; ks < 2; ++ks) {
            bf16x8 af[4], bfr[4];
            int kb = ks * 64 + ((lane >> 4) * 16);
            #pragma unroll
            for (int m = 0; m < 4; ++m) {
                int row = wm + m * 16 + (lane & 15);
                int off = (row * (BK * 2) + kb) ^ ((row & 7) << 4);
                af[m] = *(const bf16x8*)((const char*)As + off);
            }
            #pragma unroll
            for (int n = 0; n < 4; ++n) {
                int row = wn + n * 16 + (lane & 15);
                int off = (row * (BK * 2) + kb) ^ ((row & 7) << 4);
                bfr[n] = *(const bf16x8*)((const char*)Bs + off);
            }
            #pragma unroll
            for (int m = 0; m < 4; ++m)
                #pragma unroll
                for (int n = 0; n < 4; ++n)
                    acc[m][n] = __builtin_amdgcn_mfma_f32_16x16x32_bf16(
                        af[m], bfr[n], acc[m][n], 0, 0, 0);
        }
    }
    int cr = (lane >> 4) * 4;
    int cc = lane & 15;
    #pragma unroll
    for (int n = 0; n < 4; ++n) {
        int gc = col0 + wn + n * 16 + cc;
        float ps = psq[gc];
        #pragma unroll
        for (int m = 0; m < 4; ++m) {
            int grb = row0 + wm + m * 16 + cr;
            #pragma unroll
            for (int r = 0; r < 4; ++r) {
                float v = 2.0f * acc[m][n][r] - xsq[grb + r] - ps;
                out[(size_t)(grb + r) * NDIM + gc] = v;
            }
        }
    }
}

extern "C" void kernel_launch(void* const* d_in, const int* in_sizes, int n_in,
                              void* d_out, int out_size, void* d_ws, size_t ws_size,
                              hipStream_t stream) {
    const float* X = (const float*)d_in[0];
    const float* P = (const float*)d_in[1];
    float* out = (float*)d_out;

    const size_t need = (size_t)NDIM * KDIM * 2 + (size_t)NDIM * 4;  // Pbf + psq

    if (ws_size >= need) {
        short* Pbf = (short*)d_ws;                        // 1 MB
        float* psq = (float*)(Pbf + (size_t)NDIM * KDIM); // 4 KB
        convert_p<<<NDIM / 4, 256, 0, stream>>>(P, Pbf, psq);
        dist_persist<<<MDIM / ROWS, 512, 0, stream>>>(X, Pbf, psq, out);
    } else {
        float* xsq = (float*)d_ws;
        float* psq = xsq + MDIM;
        sumsq_kernel<<<(MDIM + NDIM) / 4, 256, 0, stream>>>(X, P, xsq, psq);
        dist_gemm<<<(MDIM / 128) * (NDIM / 128), 256, 0, stream>>>(X, P, xsq, psq, out);
    }
}

// Round 10
// 42.756 us; speedup vs baseline: 6.2406x; 1.1326x over previous
//
#include <hip/hip_runtime.h>
#include <hip/hip_bf16.h>

#define MDIM 16384
#define NDIM 1024
#define KDIM 512
#define BCOL 128            // cols per block (B-slice, K-complete in LDS)
#define BROW 512            // rows per block (8 waves x 64 rows)
#define NKS (KDIM / 32)     // 16 k-steps of K=32

typedef __attribute__((ext_vector_type(8))) short bf16x8;
typedef __attribute__((ext_vector_type(4))) float f32x4;

__device__ __forceinline__ short f2bf(float f) {
    union { float f; unsigned u; } v; v.f = f;
    unsigned r = v.u + 0x7fff + ((v.u >> 16) & 1);   // RNE truncate to bf16
    return (short)(r >> 16);
}

__device__ __forceinline__ bf16x8 cvt8(float4 a, float4 b) {
    bf16x8 o;
    o[0] = f2bf(a.x); o[1] = f2bf(a.y); o[2] = f2bf(a.z); o[3] = f2bf(a.w);
    o[4] = f2bf(b.x); o[5] = f2bf(b.y); o[6] = f2bf(b.z); o[7] = f2bf(b.w);
    return o;
}

__device__ __forceinline__ void gload_lds16(const void* g, void* l) {
    __builtin_amdgcn_global_load_lds(
        (const __attribute__((address_space(1))) void*)g,
        (__attribute__((address_space(3))) void*)l, 16, 0, 0);
}

// ---------- pre-pass (R2-verified): fp32->bf16 convert + exact sum-of-squares ----------
__global__ __launch_bounds__(256) void convert_sumsq(
        const float* __restrict__ X, const float* __restrict__ P,
        short* __restrict__ Xbf, short* __restrict__ Pbf,
        float* __restrict__ xsq, float* __restrict__ psq) {
    int wave = (blockIdx.x * blockDim.x + threadIdx.x) >> 6;
    int lane = threadIdx.x & 63;
    const float* src; short* dstb; float* dsts; int row;
    if (wave < MDIM) { src = X; dstb = Xbf; dsts = xsq; row = wave; }
    else             { src = P; dstb = Pbf; dsts = psq; row = wave - MDIM; }
    const float4* r4 = (const float4*)(src + (size_t)row * KDIM) + lane * 2;
    float4 a = r4[0], b = r4[1];
    *(bf16x8*)(dstb + (size_t)row * KDIM + lane * 8) = cvt8(a, b);
    float s = a.x*a.x + a.y*a.y + a.z*a.z + a.w*a.w
            + b.x*b.x + b.y*b.y + b.z*b.z + b.w*b.w;
    #pragma unroll
    for (int off = 32; off; off >>= 1) s += __shfl_down(s, off, 64);
    if (lane == 0) dsts[row] = s;
}

// ---------- barrier-free streaming GEMM ----------
// Block = 512 rows x 128 cols. B-slice (128 cols, K-complete, 128 KB) staged
// ONCE via gload_lds w16 (linear dest + pre-XOR source, rule #21; XOR confined
// to byte bits 4-6). ONE __syncthreads; then each wave runs independently:
// A-frags global->reg from Xbf (frag: row=lane&15, k=(lane>>4)*8 — verified
// R1-R9), 16 ks x 32 MFMA on a 64x128 wave tile (acc[4][8]), per-wave store
// burst at its own finish time (wave skew spreads the 67MB of stores).
__global__ __launch_bounds__(512, 2) void dist_stream(
        const short* __restrict__ Xbf, const short* __restrict__ Pbf,
        const float* __restrict__ xsq, const float* __restrict__ psq,
        float* __restrict__ out) {
    __shared__ short Bl[BCOL * KDIM];    // 128 KB

    int tid = threadIdx.x;
    int bid = blockIdx.x;
    // 256 blocks = 32 rowg x 8 colg. Dispatch round-robins XCDs on bid&7:
    // give each XCD 4 row-panels x all 8 colgs -> per-XCD L2 working set =
    // 4 x 1MB Xbf panels (8-way shared) + full Pbf (1MB).
    int xcd = bid & 7, i = bid >> 3;           // i in 0..31
    int rowg = xcd * 4 + (i & 3);              // 0..31
    int colg = i >> 2;                         // 0..7
    int row0 = rowg * BROW, col0 = colg * BCOL;

    int lane = tid & 63, wid = tid >> 6;

    // --- stage B-slice: wave (s,wid) stages column col = s*8+wid (64 x 16B) ---
    #pragma unroll
    for (int s = 0; s < 16; ++s) {
        int col = s * 8 + wid;                               // wave-uniform
        int slot2 = (lane & 56) | ((lane & 7) ^ (col & 7));  // pre-XOR source
        const char* g = (const char*)(Pbf + (size_t)(col0 + col) * KDIM)
                        + slot2 * 16;
        gload_lds16(g, (char*)Bl + col * 1024);              // + lane*16 by HW
    }
    __syncthreads();     // the ONLY barrier: B resident (drains vmcnt)

    // --- per-wave independent compute: 64 rows x 128 cols ---
    int wrow0 = row0 + wid * 64;
    const char* arow[4];
    #pragma unroll
    for (int m = 0; m < 4; ++m)
        arow[m] = (const char*)(Xbf + (size_t)(wrow0 + m * 16 + (lane & 15)) * KDIM);
    int kg16 = (lane >> 4) * 16;

    f32x4 acc[4][8] = {};
    #pragma unroll
    for (int ks = 0; ks < NKS; ++ks) {
        int kb = ks * 64 + kg16;
        bf16x8 af[4], bfr[8];
        #pragma unroll
        for (int m = 0; m < 4; ++m)
            af[m] = *(const bf16x8*)(arow[m] + kb);          // global->reg
        #pragma unroll
        for (int n = 0; n < 8; ++n) {
            int col = n * 16 + (lane & 15);
            bfr[n] = *(const bf16x8*)((const char*)Bl +
                        ((col * 1024 + kb) ^ ((col & 7) << 4)));
        }
        #pragma unroll
        for (int m = 0; m < 4; ++m)
            #pragma unroll
            for (int n = 0; n < 8; ++n)
                acc[m][n] = __builtin_amdgcn_mfma_f32_16x16x32_bf16(
                    af[m], bfr[n], acc[m][n], 0, 0, 0);
    }

    // --- epilogue (no barrier; fires as soon as this wave finishes) ---
    // C/D layout: col = lane&15, row = (lane>>4)*4 + reg  [m89]
    int cr = (lane >> 4) * 4;
    int cc = lane & 15;
    float ps[8];
    #pragma unroll
    for (int n = 0; n < 8; ++n) ps[n] = psq[col0 + n * 16 + cc];
    #pragma unroll
    for (int m = 0; m < 4; ++m) {
        #pragma unroll
        for (int r = 0; r < 4; ++r) {
            int row = wrow0 + m * 16 + cr + r;
            float xv = xsq[row];
            size_t ob = (size_t)row * NDIM + col0;
            #pragma unroll
            for (int n = 0; n < 8; ++n)
                out[ob + n * 16 + cc] = 2.0f * acc[m][n][r] - xv - ps[n];
        }
    }
}

// ---------- fallback path (R1-verified fp32 kernels, used if ws too small) ----------
__global__ __launch_bounds__(256) void sumsq_kernel(
        const float* __restrict__ X, const float* __restrict__ P,
        float* __restrict__ xsq, float* __restrict__ psq) {
    int wave = (blockIdx.x * blockDim.x + threadIdx.x) >> 6;
    int lane = threadIdx.x & 63;
    const float* src; float* dst; int row;
    if (wave < MDIM) { src = X; dst = xsq; row = wave; }
    else             { src = P; dst = psq; row = wave - MDIM; }
    const float4* r4 = (const float4*)(src + (size_t)row * KDIM) + lane * 2;
    float4 a = r4[0], b = r4[1];
    float s = a.x*a.x + a.y*a.y + a.z*a.z + a.w*a.w
            + b.x*b.x + b.y*b.y + b.z*b.z + b.w*b.w;
    #pragma unroll
    for (int off = 32; off; off >>= 1) s += __shfl_down(s, off, 64);
    if (lane == 0) dst[row] = s;
}

__global__ __launch_bounds__(256) void dist_gemm(
        const float* __restrict__ X, const float* __restrict__ P,
        const float* __restrict__ xsq, const float* __restrict__ psq,
        float* __restrict__ out) {
    __shared__ short As[128 * 64];
    __shared__ short Bs[128 * 64];
    int tid = threadIdx.x;
    int bid = blockIdx.x;
    int swz = (bid & 7) * 128 + (bid >> 3);
    int bn = swz & 7, bm = swz >> 3;
    int row0 = bm * 128, col0 = bn * 128;
    int lane = tid & 63, wid = tid >> 6;
    int wm = (wid >> 1) * 64, wn = (wid & 1) * 64;
    f32x4 acc[4][4] = {};
    int rbase = tid >> 3;
    int kg = tid & 7;
    const float* Abase = X + (size_t)row0 * KDIM;
    const float* Bbase = P + (size_t)col0 * KDIM;
    for (int kt = 0; kt < KDIM / 64; ++kt) {
        int kofs = kt * 64 + kg * 8;
        __syncthreads();
        #pragma unroll
        for (int i = 0; i < 4; ++i) {
            int row = rbase + 32 * i;
            const float4* ga = (const float4*)(Abase + (size_t)row * KDIM + kofs);
            float4 a0 = ga[0], a1 = ga[1];
            const float4* gb = (const float4*)(Bbase + (size_t)row * KDIM + kofs);
            float4 b0 = gb[0], b1 = gb[1];
            int off = (row * 128 + kg * 16) ^ ((row & 7) << 4);
            *(bf16x8*)((char*)As + off) = cvt8(a0, a1);
            *(bf16x8*)((char*)Bs + off) = cvt8(b0, b1);
        }
        __syncthreads();
        #pragma unroll
        for (int ks = 0; ks < 2; ++ks) {
            bf16x8 af[4], bfr[4];
            int kb = ks * 64 + ((lane >> 4) * 16);
            #pragma unroll
            for (int m = 0; m < 4; ++m) {
                int row = wm + m * 16 + (lane & 15);
                int off = (row * 128 + kb) ^ ((row & 7) << 4);
                af[m] = *(const bf16x8*)((const char*)As + off);
            }
            #pragma unroll
            for (int n = 0; n < 4; ++n) {
                int row = wn + n * 16 + (lane & 15);
                int off = (row * 128 + kb) ^ ((row & 7) << 4);
                bfr[n] = *(const bf16x8*)((const char*)Bs + off);
            }
            #pragma unroll
            for (int m = 0; m < 4; ++m)
                #pragma unroll
                for (int n = 0; n < 4; ++n)
                    acc[m][n] = __builtin_amdgcn_mfma_f32_16x16x32_bf16(
                        af[m], bfr[n], acc[m][n], 0, 0, 0);
        }
    }
    int cr = (lane >> 4) * 4;
    int cc = lane & 15;
    #pragma unroll
    for (int n = 0; n < 4; ++n) {
        int gc = col0 + wn + n * 16 + cc;
        float ps = psq[gc];
        #pragma unroll
        for (int m = 0; m < 4; ++m) {
            int grb = row0 + wm + m * 16 + cr;
            #pragma unroll
            for (int r = 0; r < 4; ++r) {
                float v = 2.0f * acc[m][n][r] - xsq[grb + r] - ps;
                out[(size_t)(grb + r) * NDIM + gc] = v;
            }
        }
    }
}

extern "C" void kernel_launch(void* const* d_in, const int* in_sizes, int n_in,
                              void* d_out, int out_size, void* d_ws, size_t ws_size,
                              hipStream_t stream) {
    const float* X = (const float*)d_in[0];
    const float* P = (const float*)d_in[1];
    float* out = (float*)d_out;

    const size_t bf_elems = (size_t)(MDIM + NDIM) * KDIM;      // 8,912,896
    const size_t need = bf_elems * 2 + (size_t)(MDIM + NDIM) * 4;

    if (ws_size >= need) {
        short* Xbf = (short*)d_ws;
        short* Pbf = Xbf + (size_t)MDIM * KDIM;
        float* xsq = (float*)(Xbf + bf_elems);
        float* psq = xsq + MDIM;
        convert_sumsq<<<(MDIM + NDIM) / 4, 256, 0, stream>>>(X, P, Xbf, Pbf, xsq, psq);
        dist_stream<<<(MDIM / BROW) * (NDIM / BCOL), 512, 0, stream>>>(Xbf, Pbf, xsq, psq, out);
    } else {
        float* xsq = (float*)d_ws;
        float* psq = xsq + MDIM;
        sumsq_kernel<<<(MDIM + NDIM) / 4, 256, 0, stream>>>(X, P, xsq, psq);
        dist_gemm<<<(MDIM / 128) * (NDIM / 128), 256, 0, stream>>>(X, P, xsq, psq, out);
    }
}